// Round 5
// baseline (457.324 us; speedup 1.0000x reference)
//
#include <hip/hip_runtime.h>
#include <hip/hip_bf16.h>
#include <math.h>

// Problem constants (B=2, S=2048, D=1024, H=16, DH=64)
#define BB 2
#define SS 2048
#define DD 1024
#define HH 16
#define DH 64
#define NTOK (BB * SS)   // 4096
#define LN_EPS 1e-5f
#define BIGNEG -1e30f

typedef __attribute__((ext_vector_type(8))) short bf16x8;   // 8 bf16 = 4 VGPRs
typedef __attribute__((ext_vector_type(4))) float f32x4;    // MFMA accumulator

static __device__ __forceinline__ float b2f(unsigned short u) {
    return __uint_as_float(((unsigned)u) << 16);
}
static __device__ __forceinline__ unsigned short f2bu(float f) {
    __hip_bfloat16 h = __float2bfloat16(f);
    return *(unsigned short*)&h;
}

// async 16B global -> LDS. LDS dest must be wave-uniform base + lane*16.
static __device__ __forceinline__ void async16(const void* g, void* l) {
    __builtin_amdgcn_global_load_lds((const __attribute__((address_space(1))) void*)g,
                                     (__attribute__((address_space(3))) void*)l, 16, 0, 0);
}

// ---------------------------------------------------------------------------
// Merged weight transpose+cast for all 6 weights: one launch, 10240 tiles.
// Wt[n][k] = bf16(W[k][n]).
// ---------------------------------------------------------------------------
__global__ __launch_bounds__(256) void transpose_all(const float* __restrict__ Wq,
                                                     const float* __restrict__ Wk,
                                                     const float* __restrict__ Wv,
                                                     const float* __restrict__ Wo,
                                                     const float* __restrict__ W1,
                                                     const float* __restrict__ W2,
                                                     __hip_bfloat16* __restrict__ wqkvt,
                                                     __hip_bfloat16* __restrict__ wot,
                                                     __hip_bfloat16* __restrict__ w1t,
                                                     __hip_bfloat16* __restrict__ w2t) {
    const int bid = blockIdx.x;
    const float* W;
    __hip_bfloat16* Wt;
    int K, N, tile;
    if (bid < 4096) {                 // Wq,Wk,Wv,Wo: 1024x1024, 1024 tiles each
        const int m = bid >> 10;
        tile = bid & 1023;
        W = (m == 0) ? Wq : (m == 1) ? Wk : (m == 2) ? Wv : Wo;
        Wt = (m < 3) ? (wqkvt + (size_t)m * 1024 * 1024) : wot;
        K = 1024; N = 1024;
    } else if (bid < 8192) {          // W1: 1024x4096
        tile = bid - 4096; W = W1; Wt = w1t; K = 1024; N = 4096;
    } else {                          // W2: 2048x1024
        tile = bid - 8192; W = W2; Wt = w2t; K = 2048; N = 1024;
    }
    const int nt = N >> 5;
    const int n0 = (tile % nt) * 32, k0 = (tile / nt) * 32;

    __shared__ float t[32][33];
    const int tx = threadIdx.x & 31, ty = threadIdx.x >> 5;  // ty 0..7
#pragma unroll
    for (int i = 0; i < 4; ++i)
        t[ty + 8 * i][tx] = W[(size_t)(k0 + ty + 8 * i) * N + n0 + tx];
    __syncthreads();
#pragma unroll
    for (int i = 0; i < 4; ++i)
        Wt[(size_t)(n0 + ty + 8 * i) * K + k0 + tx] = __float2bfloat16(t[tx][ty + 8 * i]);
}

// ---------------------------------------------------------------------------
// LayerNorm fp32 -> bf16. One block per row, D=1024.
// ---------------------------------------------------------------------------
__global__ __launch_bounds__(256) void ln_kernel(const float* __restrict__ x,
                                                 const float* __restrict__ gamma,
                                                 const float* __restrict__ beta,
                                                 __hip_bfloat16* __restrict__ out) {
    const int row = blockIdx.x;
    const int tid = threadIdx.x;
    __shared__ float red[256];

    const float* xp = x + (size_t)row * DD;
    float vals[4];
    float s = 0.f;
#pragma unroll
    for (int i = 0; i < 4; ++i) {
        float v = xp[tid + i * 256];
        vals[i] = v;
        s += v;
    }
    red[tid] = s;
    __syncthreads();
    for (int st = 128; st > 0; st >>= 1) {
        if (tid < st) red[tid] += red[tid + st];
        __syncthreads();
    }
    const float mu = red[0] * (1.0f / DD);
    __syncthreads();
    float sq = 0.f;
#pragma unroll
    for (int i = 0; i < 4; ++i) {
        float d = vals[i] - mu;
        sq += d * d;
    }
    red[tid] = sq;
    __syncthreads();
    for (int st = 128; st > 0; st >>= 1) {
        if (tid < st) red[tid] += red[tid + st];
        __syncthreads();
    }
    const float rinv = rsqrtf(red[0] * (1.0f / DD) + LN_EPS);

    __hip_bfloat16* op = out + (size_t)row * DD;
#pragma unroll
    for (int i = 0; i < 4; ++i) {
        int j = tid + i * 256;
        op[j] = __float2bfloat16(gamma[j] * ((vals[i] - mu) * rinv) + beta[j]);
    }
}

// ---------------------------------------------------------------------------
// MFMA bf16 GEMM (m97 structure): C[M,N] = A[M,K] @ Bt[N,K]^T
// 128x128 tile, 4 waves, BK=64, global_load_lds staging.
// RES: 0 none, 1 add fp32 res[oi].  EPI: 0 fp32 out, 1 bf16 out.
// ---------------------------------------------------------------------------
template <int RES, int EPI>
__global__ __launch_bounds__(256) void mfma_gemm(const __hip_bfloat16* __restrict__ A,
                                                 const __hip_bfloat16* __restrict__ Bt,
                                                 const void* __restrict__ res,
                                                 void* __restrict__ out,
                                                 int M, int N, int K) {
    __shared__ short As[128 * 64];
    __shared__ short Bs[128 * 64];
    const int tid = threadIdx.x;
    const int lane = tid & 63;
    const int wave = tid >> 6;
    const int row0 = blockIdx.y * 128;
    const int col0 = blockIdx.x * 128;
    const int wr = (wave >> 1) * 64;
    const int wc = (wave & 1) * 64;
    const int l15 = lane & 15;
    const int lk8 = (lane >> 4) * 8;

    f32x4 acc[4][4] = {};

    for (int k0 = 0; k0 < K; k0 += 64) {
#pragma unroll
        for (int r = 0; r < 4; ++r) {
            const int e = (r * 256 + tid) * 8;
            const int ar = e >> 6, ac = e & 63;
            async16(&A[(size_t)(row0 + ar) * K + k0 + ac], &As[e]);
            async16(&Bt[(size_t)(col0 + ar) * K + k0 + ac], &Bs[e]);
        }
        __syncthreads();
#pragma unroll
        for (int kk = 0; kk < 2; ++kk) {
            bf16x8 af[4], bfr[4];
#pragma unroll
            for (int i = 0; i < 4; ++i)
                af[i] = *(const bf16x8*)&As[(wr + i * 16 + l15) * 64 + kk * 32 + lk8];
#pragma unroll
            for (int j = 0; j < 4; ++j)
                bfr[j] = *(const bf16x8*)&Bs[(wc + j * 16 + l15) * 64 + kk * 32 + lk8];
#pragma unroll
            for (int i = 0; i < 4; ++i)
#pragma unroll
                for (int j = 0; j < 4; ++j)
                    acc[i][j] = __builtin_amdgcn_mfma_f32_16x16x32_bf16(af[i], bfr[j], acc[i][j], 0, 0, 0);
        }
        __syncthreads();
    }

    const int r4 = (lane >> 4) * 4;
#pragma unroll
    for (int i = 0; i < 4; ++i) {
#pragma unroll
        for (int j = 0; j < 4; ++j) {
#pragma unroll
            for (int rg = 0; rg < 4; ++rg) {
                const int orow = row0 + wr + i * 16 + r4 + rg;
                const int ocol = col0 + wc + j * 16 + l15;
                const size_t oi = (size_t)orow * N + ocol;
                float v = acc[i][j][rg];
                if constexpr (RES == 1) v += ((const float*)res)[oi];
                if constexpr (EPI == 0) ((float*)out)[oi] = v;
                if constexpr (EPI == 1) ((__hip_bfloat16*)out)[oi] = __float2bfloat16(v);
            }
        }
    }
}

// ---------------------------------------------------------------------------
// Fused FFN-in GEMM+GLU: glu[4096,2048] = (A@W1L^T) * sigmoid(A@W1R^T), bf16.
// w1t is [4096][1024] (n-major); left = rows [0,2048), right = rows [2048,4096).
// 128x128 tile, dual accumulators, single A staging.
// ---------------------------------------------------------------------------
__global__ __launch_bounds__(256) void mfma_gemm_glu(const __hip_bfloat16* __restrict__ A,
                                                     const __hip_bfloat16* __restrict__ Bt,
                                                     __hip_bfloat16* __restrict__ out) {
    __shared__ short As[128 * 64];
    __shared__ short Bl[128 * 64];
    __shared__ short Br[128 * 64];
    const int tid = threadIdx.x;
    const int lane = tid & 63;
    const int wave = tid >> 6;
    const int row0 = blockIdx.y * 128;
    const int col0 = blockIdx.x * 128;
    const int wr = (wave >> 1) * 64;
    const int wc = (wave & 1) * 64;
    const int l15 = lane & 15;
    const int lk8 = (lane >> 4) * 8;

    f32x4 accl[4][4] = {};
    f32x4 accr[4][4] = {};

    for (int k0 = 0; k0 < 1024; k0 += 64) {
#pragma unroll
        for (int r = 0; r < 4; ++r) {
            const int e = (r * 256 + tid) * 8;
            const int ar = e >> 6, ac = e & 63;
            async16(&A[(size_t)(row0 + ar) * 1024 + k0 + ac], &As[e]);
            async16(&Bt[(size_t)(col0 + ar) * 1024 + k0 + ac], &Bl[e]);
            async16(&Bt[(size_t)(2048 + col0 + ar) * 1024 + k0 + ac], &Br[e]);
        }
        __syncthreads();
#pragma unroll
        for (int kk = 0; kk < 2; ++kk) {
            bf16x8 af[4], bl[4], br[4];
#pragma unroll
            for (int i = 0; i < 4; ++i)
                af[i] = *(const bf16x8*)&As[(wr + i * 16 + l15) * 64 + kk * 32 + lk8];
#pragma unroll
            for (int j = 0; j < 4; ++j) {
                bl[j] = *(const bf16x8*)&Bl[(wc + j * 16 + l15) * 64 + kk * 32 + lk8];
                br[j] = *(const bf16x8*)&Br[(wc + j * 16 + l15) * 64 + kk * 32 + lk8];
            }
#pragma unroll
            for (int i = 0; i < 4; ++i)
#pragma unroll
                for (int j = 0; j < 4; ++j) {
                    accl[i][j] = __builtin_amdgcn_mfma_f32_16x16x32_bf16(af[i], bl[j], accl[i][j], 0, 0, 0);
                    accr[i][j] = __builtin_amdgcn_mfma_f32_16x16x32_bf16(af[i], br[j], accr[i][j], 0, 0, 0);
                }
        }
        __syncthreads();
    }

    const int r4 = (lane >> 4) * 4;
#pragma unroll
    for (int i = 0; i < 4; ++i) {
#pragma unroll
        for (int j = 0; j < 4; ++j) {
#pragma unroll
            for (int rg = 0; rg < 4; ++rg) {
                const int orow = row0 + wr + i * 16 + r4 + rg;
                const int ocol = col0 + wc + j * 16 + l15;
                const float l = accl[i][j][rg];
                const float r = accr[i][j][rg];
                out[(size_t)orow * 2048 + ocol] =
                    __float2bfloat16(l * (1.f / (1.f + __expf(-r))));
            }
        }
    }
}

// ---------------------------------------------------------------------------
// MFMA flash attention, 64-query blocks for occupancy + reversed-qt balance.
// Block = 256 threads (4 waves); wave owns 16 queries. K loop in 64-key LDS
// chunks: Ks [key][dim] (global_load_lds), Vt [dim][key] stride 72, P per-wave
// [q][key] stride 72 (LDS round-trip C-layout -> A-layout). Online softmax per
// reg-row with 16-lane shfl_xor reductions.
// ---------------------------------------------------------------------------
#define VSTR 72
__global__ __launch_bounds__(256) void flash_mfma(const __hip_bfloat16* __restrict__ qkv_,
                                                  const int* __restrict__ mask,
                                                  __hip_bfloat16* __restrict__ attnb) {
    const unsigned short* qkv = (const unsigned short*)qkv_;
    __shared__ __align__(16) short Ks[64 * 64];
    __shared__ __align__(16) short Vt[64 * VSTR];
    __shared__ __align__(16) short Ps[4][16 * VSTR];
    __shared__ float Ms[64];

    const int tid = threadIdx.x;
    const int lane = tid & 63;
    const int wave = tid >> 6;
    const int l15 = lane & 15;
    const int quad = lane >> 4;
    const int qt = 31 - (blockIdx.x & 31);     // reversed: long blocks dispatch first
    const int h = (blockIdx.x >> 5) & 15;
    const int b = blockIdx.x >> 9;
    const int q0 = qt * 64 + wave * 16;        // wave's first query

    // Q fragments (A-layout): m=lane&15 -> query, k=quad*8+j -> dim
    bf16x8 aq[2];
#pragma unroll
    for (int ks = 0; ks < 2; ++ks)
        aq[ks] = *(const bf16x8*)(qkv + (size_t)(b * SS + q0 + l15) * 3072 +
                                  h * 64 + ks * 32 + quad * 8);

    f32x4 O[4];
    float m_r[4], l_r[4];
#pragma unroll
    for (int i = 0; i < 4; ++i) {
        O[i] = (f32x4){0.f, 0.f, 0.f, 0.f};
        m_r[i] = BIGNEG;
        l_r[i] = 0.f;
    }

    const int nch = qt + 1;
    for (int c = 0; c < nch; ++c) {
        const int kb = c * 64;
        __syncthreads();  // protect prev-iter LDS reads before overwrite
        // stage K chunk: 64x64 bf16 via global_load_lds (2 rounds x 256 x 16B)
#pragma unroll
        for (int r = 0; r < 2; ++r) {
            const int e8 = (r * 256 + tid) * 8;
            const int key = e8 >> 6, dim = e8 & 63;
            async16(qkv + (size_t)(b * SS + kb + key) * 3072 + 1024 + h * 64 + dim, &Ks[e8]);
        }
        // stage V transposed: Vt[dim][key], stride 72; wave w covers dims [16w,16w+16)
        {
            const int key = lane;
            const int d0 = wave * 16;
            const unsigned short* vp =
                qkv + (size_t)(b * SS + kb + key) * 3072 + 2048 + h * 64 + d0;
#pragma unroll
            for (int i = 0; i < 4; ++i) {
                const ushort4 u = *(const ushort4*)(vp + 4 * i);
                Vt[(d0 + 4 * i + 0) * VSTR + key] = (short)u.x;
                Vt[(d0 + 4 * i + 1) * VSTR + key] = (short)u.y;
                Vt[(d0 + 4 * i + 2) * VSTR + key] = (short)u.z;
                Vt[(d0 + 4 * i + 3) * VSTR + key] = (short)u.w;
            }
        }
        if (tid < 64) Ms[tid] = mask[b * SS + kb + tid] ? 1.f : 0.f;
        __syncthreads();

        // ---- S = Q K^T (C-layout: col=key-in-tile, row=query-in-tile)
        f32x4 S[4];
#pragma unroll
        for (int kt = 0; kt < 4; ++kt) {
            const bf16x8 bk0 = *(const bf16x8*)&Ks[(kt * 16 + l15) * 64 + quad * 8];
            const bf16x8 bk1 = *(const bf16x8*)&Ks[(kt * 16 + l15) * 64 + 32 + quad * 8];
            f32x4 z = {0.f, 0.f, 0.f, 0.f};
            z = __builtin_amdgcn_mfma_f32_16x16x32_bf16(aq[0], bk0, z, 0, 0, 0);
            S[kt] = __builtin_amdgcn_mfma_f32_16x16x32_bf16(aq[1], bk1, z, 0, 0, 0);
        }
        // ---- causal + attention mask + scale
        float msk[4];
#pragma unroll
        for (int kt = 0; kt < 4; ++kt) msk[kt] = Ms[kt * 16 + l15];
        const int qrow = q0 + quad * 4;
#pragma unroll
        for (int kt = 0; kt < 4; ++kt) {
            const int key = kb + kt * 16 + l15;
#pragma unroll
            for (int rg = 0; rg < 4; ++rg) {
                const bool valid = (key <= qrow + rg) && (msk[kt] != 0.f);
                S[kt][rg] = valid ? S[kt][rg] * 0.125f : BIGNEG;
            }
        }
        // ---- online softmax (row reduce across the 16 lanes of the quad)
        float alpha[4];
#pragma unroll
        for (int rg = 0; rg < 4; ++rg) {
            float v = fmaxf(fmaxf(S[0][rg], S[1][rg]), fmaxf(S[2][rg], S[3][rg]));
            v = fmaxf(v, __shfl_xor(v, 1));
            v = fmaxf(v, __shfl_xor(v, 2));
            v = fmaxf(v, __shfl_xor(v, 4));
            v = fmaxf(v, __shfl_xor(v, 8));
            const float mn = fmaxf(m_r[rg], v);
            const float al = __expf(m_r[rg] - mn);
            m_r[rg] = mn;
            alpha[rg] = al;
            l_r[rg] *= al;
        }
#pragma unroll
        for (int kt = 0; kt < 4; ++kt)
#pragma unroll
            for (int rg = 0; rg < 4; ++rg)
                S[kt][rg] = __expf(S[kt][rg] - m_r[rg]);
#pragma unroll
        for (int rg = 0; rg < 4; ++rg) {
            float v = S[0][rg] + S[1][rg] + S[2][rg] + S[3][rg];
            v += __shfl_xor(v, 1);
            v += __shfl_xor(v, 2);
            v += __shfl_xor(v, 4);
            v += __shfl_xor(v, 8);
            l_r[rg] += v;
        }
        // ---- rescale O
#pragma unroll
        for (int nt = 0; nt < 4; ++nt)
#pragma unroll
            for (int rg = 0; rg < 4; ++rg)
                O[nt][rg] *= alpha[rg];
        // ---- P: C-layout regs -> per-wave LDS -> A-layout frags
        short* Pw = &Ps[wave][0];
#pragma unroll
        for (int kt = 0; kt < 4; ++kt)
#pragma unroll
            for (int rg = 0; rg < 4; ++rg)
                Pw[(quad * 4 + rg) * VSTR + kt * 16 + l15] = (short)f2bu(S[kt][rg]);
        asm volatile("s_waitcnt lgkmcnt(0)" ::: "memory");
        // ---- O += P V
        {
            const bf16x8 ap0 = *(const bf16x8*)&Pw[l15 * VSTR + quad * 8];
            const bf16x8 ap1 = *(const bf16x8*)&Pw[l15 * VSTR + 32 + quad * 8];
#pragma unroll
            for (int nt = 0; nt < 4; ++nt) {
                const bf16x8 bv0 = *(const bf16x8*)&Vt[(nt * 16 + l15) * VSTR + quad * 8];
                const bf16x8 bv1 = *(const bf16x8*)&Vt[(nt * 16 + l15) * VSTR + 32 + quad * 8];
                O[nt] = __builtin_amdgcn_mfma_f32_16x16x32_bf16(ap0, bv0, O[nt], 0, 0, 0);
                O[nt] = __builtin_amdgcn_mfma_f32_16x16x32_bf16(ap1, bv1, O[nt], 0, 0, 0);
            }
        }
    }

    // epilogue: O /= l, write bf16
#pragma unroll
    for (int rg = 0; rg < 4; ++rg) {
        const int q = q0 + quad * 4 + rg;
        const float inv = 1.f / l_r[rg];
        unsigned short* op = (unsigned short*)attnb + (size_t)(b * SS + q) * 1024 + h * 64;
#pragma unroll
        for (int nt = 0; nt < 4; ++nt)
            op[nt * 16 + l15] = f2bu(O[nt][rg] * inv);
    }
}

// ---------------------------------------------------------------------------
// Launch. Workspace plan (60 MB peak), offsets in bytes:
//   [0,6M)   Wqkv_t bf16 [3072][1024]
//   [6,8M)   Wo_t   bf16 [1024][1024]
//   [8,16M)  W1_t   bf16 [4096][1024]
//   [16,20M) W2_t   bf16 [1024][2048]
//   [20,28M) lnb    bf16 (ln1 then ln2)
//   [28,52M) qkvb   bf16 [4096][3072]   -> dead after flash
//   [28,44M) x1     fp32                (reuses qkvb head)
//   [52,60M) attnb  bf16                -> dead after Wo gemm
//   [44,60M) glub   bf16 [4096][2048]
// ---------------------------------------------------------------------------
extern "C" void kernel_launch(void* const* d_in, const int* in_sizes, int n_in,
                              void* d_out, int out_size, void* d_ws, size_t ws_size,
                              hipStream_t stream) {
    const float* x  = (const float*)d_in[0];
    const int* mask = (const int*)d_in[1];
    const float* Wq = (const float*)d_in[2];
    const float* Wk = (const float*)d_in[3];
    const float* Wv = (const float*)d_in[4];
    const float* Wo = (const float*)d_in[5];
    const float* W1 = (const float*)d_in[6];
    const float* W2 = (const float*)d_in[7];
    const float* g1 = (const float*)d_in[8];
    const float* b1 = (const float*)d_in[9];
    const float* g2 = (const float*)d_in[10];
    const float* b2 = (const float*)d_in[11];

    const size_t MB = 1024 * 1024;
    uint8_t* ws = (uint8_t*)d_ws;
    __hip_bfloat16* wqkvt = (__hip_bfloat16*)(ws);
    __hip_bfloat16* wot   = (__hip_bfloat16*)(ws + 6 * MB);
    __hip_bfloat16* w1t   = (__hip_bfloat16*)(ws + 8 * MB);
    __hip_bfloat16* w2t   = (__hip_bfloat16*)(ws + 16 * MB);
    __hip_bfloat16* lnb   = (__hip_bfloat16*)(ws + 20 * MB);
    __hip_bfloat16* qkvb  = (__hip_bfloat16*)(ws + 28 * MB);
    float*          x1    = (float*)(ws + 28 * MB);
    __hip_bfloat16* glub  = (__hip_bfloat16*)(ws + 44 * MB);
    __hip_bfloat16* attnb = (__hip_bfloat16*)(ws + 52 * MB);

    // 0. all weight transposes in one launch
    transpose_all<<<10240, 256, 0, stream>>>(Wq, Wk, Wv, Wo, W1, W2, wqkvt, wot, w1t, w2t);

    // 1. ln1 = LN(x) -> lnb
    ln_kernel<<<NTOK, 256, 0, stream>>>(x, g1, b1, lnb);

    // 2. qkv = ln1 @ [Wq|Wk|Wv] -> qkvb (N=3072)
    mfma_gemm<0, 1><<<dim3(24, 32), 256, 0, stream>>>(lnb, wqkvt, nullptr, qkvb, NTOK, 3072, 1024);

    // 3. MFMA flash attention -> attnb (1024 blocks, reversed qt)
    flash_mfma<<<BB * HH * 32, 256, 0, stream>>>(qkvb, mask, attnb);

    // 4. x1 = x + attn @ Wo -> x1 (fp32)
    mfma_gemm<1, 0><<<dim3(8, 32), 256, 0, stream>>>(attnb, wot, x, x1, NTOK, 1024, 1024);

    // 5. ln2 = LN(x1) -> lnb
    ln_kernel<<<NTOK, 256, 0, stream>>>(x1, g2, b2, lnb);

    // 6. glu = (ln2@W1L) * sigmoid(ln2@W1R) -> glub (fused)
    mfma_gemm_glu<<<dim3(16, 32), 256, 0, stream>>>(lnb, w1t, glub);

    // 7. out = x1 + glu @ W2 -> d_out (fp32)
    mfma_gemm<1, 0><<<dim3(8, 32), 256, 0, stream>>>(glub, w2t, x1, (float*)d_out,
                                                     NTOK, 1024, 2048);
}